// Round 1
// baseline (578.868 us; speedup 1.0000x reference)
//
#include <hip/hip_runtime.h>
#include <math.h>

#define NUM_K 128
#define DIM   256
#define NROWS (64 * 2048)     // 131072
#define BLOCK 256
#define GRID  (NROWS / BLOCK) // 512

// flat fp32 output offsets (reference tuple order)
#define OFF_LOSS 0u
#define OFF_Q    1u
#define OFF_PERP 33554433u
#define OFF_ENC  33554434u
#define OFF_IDX  50331650u

// ws float layout: [0] loss accumulator; ints at float-idx [64..191] counts; [256..383] se[k]

__global__ void vq_setup(const float* __restrict__ E, float* __restrict__ ws) {
    int t = threadIdx.x;            // 128 threads
    if (t == 0) ws[0] = 0.0f;
    ((int*)ws)[64 + t] = 0;
    float s = 0.0f;
    for (int d = 0; d < DIM; ++d) { float v = E[t * DIM + d]; s += v * v; }
    ws[256 + t] = s;
}

__global__ __launch_bounds__(BLOCK, 2) void vq_main(
        const float* __restrict__ X, const float* __restrict__ E,
        float* ws, float* __restrict__ out) {
    const int tid = threadIdx.x;
    const int row = blockIdx.x * BLOCK + tid;
    const float* xrow = X + (size_t)row * DIM;

    float acc[NUM_K];
    #pragma unroll
    for (int k = 0; k < NUM_K; ++k) acc[k] = 0.0f;
    float sx = 0.0f;

    // dc chunks of 16 keep the fully-unrolled k-body ~2K instrs (I$-friendly)
    for (int dc = 0; dc < DIM; dc += 16) {
        float xr[16];
        #pragma unroll
        for (int j = 0; j < 4; ++j) {
            float4 v = *(const float4*)(xrow + dc + 4 * j);
            xr[4*j+0] = v.x; xr[4*j+1] = v.y; xr[4*j+2] = v.z; xr[4*j+3] = v.w;
        }
        #pragma unroll
        for (int j = 0; j < 16; ++j) sx = fmaf(xr[j], xr[j], sx);
        #pragma unroll
        for (int k = 0; k < NUM_K; ++k) {
            // uniform indices -> scalar (s_load) codebook reads
            const float* erow = E + k * DIM + dc;
            float s = 0.0f;
            #pragma unroll
            for (int j = 0; j < 16; ++j) s = fmaf(xr[j], erow[j], s);
            acc[k] += s;   // 128 independent chains; scheduler interleaves
        }
    }

    // argmin over t_k = ||e_k||^2 - 2 x.e_k  (||x||^2 shift doesn't change order)
    float dmin = INFINITY; int idx = 0;
    #pragma unroll
    for (int k = 0; k < NUM_K; ++k) {
        float t = ws[256 + k] - 2.0f * acc[k];
        if (t < dmin) { dmin = t; idx = k; }   // strict <: first index on ties (np semantics)
    }

    out[OFF_IDX + row] = (float)idx;

    // loss partial: ||x - e_idx||^2 = sx + dmin ; wave-reduce then one atomic per wave
    float v = sx + dmin;
    #pragma unroll
    for (int off = 32; off; off >>= 1) v += __shfl_down(v, off);
    if ((tid & 63) == 0) atomicAdd(&ws[0], v);

    __shared__ int idxs[BLOCK];
    __shared__ int hcnt[NUM_K];
    if (tid < NUM_K) hcnt[tid] = 0;
    idxs[tid] = idx;
    __syncthreads();
    atomicAdd(&hcnt[idx], 1);
    __syncthreads();
    if (tid < NUM_K) atomicAdd((int*)ws + 64 + tid, hcnt[tid]);

    // ---- write phase (coalesced) ----
    const int r0 = blockIdx.x * BLOCK;
    const int lane = tid & 63;
    const int sub  = tid >> 6;          // 0..3

    // quantized: 4 rows per iteration, scalar dword stores (OFF_Q=1 breaks 16B align)
    for (int rb = 0; rb < BLOCK; rb += 4) {
        int r = rb + sub;
        const float* erow = E + (size_t)idxs[r] * DIM;
        size_t base = OFF_Q + (size_t)(r0 + r) * DIM;
        #pragma unroll
        for (int j = 0; j < 4; ++j)
            out[base + lane + 64 * j] = erow[lane + 64 * j];
    }

    // encodings one-hot: float2 stores (OFF_ENC even -> 8B aligned)
    for (int rb = 0; rb < BLOCK; rb += 4) {
        int r = rb + sub;
        int ir = idxs[r];
        int kp = lane * 2;
        float2 e2;
        e2.x = (kp     == ir) ? 1.0f : 0.0f;
        e2.y = (kp + 1 == ir) ? 1.0f : 0.0f;
        *(float2*)(out + OFF_ENC + (size_t)(r0 + r) * NUM_K + kp) = e2;
    }
}

__global__ void vq_final(const float* __restrict__ ws, float* __restrict__ out) {
    int t = threadIdx.x;   // 128 threads
    if (t == 0) out[OFF_LOSS] = 0.25f * (ws[0] / (float)((size_t)NROWS * DIM));
    int c = ((const int*)ws)[64 + t];
    float p = (float)c / (float)NROWS;
    float v = p * logf(p + 1e-10f);
    #pragma unroll
    for (int off = 32; off; off >>= 1) v += __shfl_down(v, off);
    __shared__ float red[2];
    if ((t & 63) == 0) red[t >> 6] = v;
    __syncthreads();
    if (t == 0) out[OFF_PERP] = expf(-(red[0] + red[1]));
}

extern "C" void kernel_launch(void* const* d_in, const int* in_sizes, int n_in,
                              void* d_out, int out_size, void* d_ws, size_t ws_size,
                              hipStream_t stream) {
    const float* X = (const float*)d_in[0];   // [64,2048,256] fp32
    const float* E = (const float*)d_in[1];   // [128,256] fp32
    float* out = (float*)d_out;
    float* ws  = (float*)d_ws;                // needs >= 1536 bytes

    vq_setup<<<1, 128, 0, stream>>>(E, ws);
    vq_main <<<GRID, BLOCK, 0, stream>>>(X, E, ws, out);
    vq_final<<<1, 128, 0, stream>>>(ws, out);
}